// Round 4
// baseline (244.554 us; speedup 1.0000x reference)
//
#include <hip/hip_runtime.h>

// SSIM loss, fused single-pass separable box filter — shuffle halo +
// software-pipelined loads. R4: __launch_bounds__(256,4) raises the VGPR cap
// to 128 (grid supplies exactly 4 waves/SIMD, so no occupancy loss) so the
// prefetch buffers actually stay live; warm-up is a 2-ahead rolling pipeline.
//
// Grid: 1024 blocks = 64 images x 16 row-bands. Block = 256 threads = 4
// independent waves (no __syncthreads in the hot loop). Each wave owns SH=8
// output rows x 512 cols; each lane owns 8 contiguous columns.
// Vertical 11-row window: per-lane register running sums; add-row prefetched
// one iteration ahead, sub-row (L1-resident, touched 11 rows ago) issued at
// iteration top and consumed after hsum+SSIM.
// Horizontal 11-col window: 5-float halo per side via __shfl.

#define IMG_H 512
#define IMG_W 512
#define N_IMG 64
#define RAD   5
#define SH    8
#define NBAND 16
#define NBLOCKS (N_IMG * NBAND)

#define C1_SSIM 1.0e-4f
#define C2_SSIM 9.0e-4f

__global__ __launch_bounds__(256, 4) void ssim_fused(const float* __restrict__ x,
                                                     const float* __restrict__ y,
                                                     float* __restrict__ acc,
                                                     unsigned int* __restrict__ cnt,
                                                     float* __restrict__ out)
{
    const int tx  = threadIdx.x & 63;
    const int ts  = threadIdx.x >> 6;
    const int img = blockIdx.x >> 4;          // / NBAND
    const int bnd = blockIdx.x & (NBAND - 1);
    const int r0  = bnd * (4 * SH) + ts * SH;
    const int c0  = tx * 8;

    const float* __restrict__ xb = x + (size_t)img * (IMG_H * IMG_W) + c0;
    const float* __restrict__ yb = y + (size_t)img * (IMG_H * IMG_W) + c0;

    float Vx[8], Vy[8], Vxx[8], Vyy[8], Vxy[8];
#pragma unroll
    for (int j = 0; j < 8; ++j) { Vx[j] = 0.f; Vy[j] = 0.f; Vxx[j] = 0.f; Vyy[j] = 0.f; Vxy[j] = 0.f; }

    struct RowBuf { float4 x0, x1, y0, y1; float sc; };

    // branchless clamped row load; sc=0 zeroes the contribution of pad rows
    auto loadrow = [&](int ri) -> RowBuf {
        RowBuf b;
        int rc = ri < 0 ? 0 : (ri > IMG_H - 1 ? IMG_H - 1 : ri);
        b.sc = (ri >= 0 && ri < IMG_H) ? 1.0f : 0.0f;
        const float4* xr = (const float4*)(xb + (size_t)rc * IMG_W);
        const float4* yr = (const float4*)(yb + (size_t)rc * IMG_W);
        b.x0 = xr[0]; b.x1 = xr[1]; b.y0 = yr[0]; b.y1 = yr[1];
        return b;
    };

    // V += sgn * sc * (row moments); sc in {0,1} so sc^2 == sc keeps xx/yy/xy right
    auto apply = [&](const RowBuf& b, float sgn) {
        const float f = b.sc * sgn;
        float xs[8] = {b.x0.x, b.x0.y, b.x0.z, b.x0.w, b.x1.x, b.x1.y, b.x1.z, b.x1.w};
        float ys[8] = {b.y0.x, b.y0.y, b.y0.z, b.y0.w, b.y1.x, b.y1.y, b.y1.z, b.y1.w};
#pragma unroll
        for (int j = 0; j < 8; ++j) {
            float fx = f * xs[j];
            float fy = f * ys[j];
            Vx[j] += fx;
            Vy[j] += fy;
            Vxx[j] = fmaf(fx, xs[j], Vxx[j]);
            Vyy[j] = fmaf(fy, ys[j], Vyy[j]);
            Vxy[j] = fmaf(fx, ys[j], Vxy[j]);
        }
    };

    // 11-tap sliding horizontal sums; halo via lane+-1 shuffles
    auto hsum = [&](const float (&V)[8], float (&S)[8]) {
        float w[18];
#pragma unroll
        for (int k = 0; k < 5; ++k) {
            float l = __shfl_up(V[3 + k], 1, 64);
            w[k] = (tx == 0) ? 0.f : l;
        }
#pragma unroll
        for (int j = 0; j < 8; ++j) w[5 + j] = V[j];
#pragma unroll
        for (int k = 0; k < 5; ++k) {
            float r = __shfl_down(V[k], 1, 64);
            w[13 + k] = (tx == 63) ? 0.f : r;
        }
        float s = 0.f;
#pragma unroll
        for (int t = 0; t < 11; ++t) s += w[t];
        S[0] = s;
#pragma unroll
        for (int j = 1; j < 8; ++j) { s += w[j + 10] - w[j - 1]; S[j] = s; }
    };

    // ---- warm-up: apply rows r0-5 .. r0+4 with a 2-ahead rolling pipeline ----
    RowBuf w0 = loadrow(r0 - 5);
    RowBuf w1 = loadrow(r0 - 4);
#pragma unroll
    for (int i = 0; i < 8; ++i) {               // applies r0-5 .. r0+2
        RowBuf w2 = loadrow(r0 - 3 + i);        // loads  r0-3 .. r0+4
        apply(w0, 1.0f);
        w0 = w1; w1 = w2;
    }
    RowBuf curA = loadrow(r0 + RAD);            // first add-row, in flight
    apply(w0, 1.0f);                            // r0+3
    apply(w1, 1.0f);                            // r0+4  -> V = [r0-5, r0+4]

    const float inv121 = 1.0f / 121.0f;
    float loss = 0.0f;

    for (int ro = r0; ro < r0 + SH; ++ro) {
        RowBuf nxtA = loadrow(ro + RAD + 1);    // next add-row (1-iter prefetch)
        RowBuf sub  = loadrow(ro - RAD);        // this iter's sub-row (L1-hit)

        apply(curA, 1.0f);                      // V covers rows [ro-5, ro+5]

        float Sx[8], Sy[8], Sxx[8], Syy[8], Sxy[8];
        hsum(Vx,  Sx);
        hsum(Vy,  Sy);
        hsum(Vxx, Sxx);
        hsum(Vyy, Syy);
        hsum(Vxy, Sxy);

#pragma unroll
        for (int j = 0; j < 8; ++j) {
            float mx  = Sx[j] * inv121;
            float my  = Sy[j] * inv121;
            float mx2 = mx * mx;
            float my2 = my * my;
            float mxy = mx * my;
            float vx  = Sxx[j] * inv121 - mx2;
            float vy  = Syy[j] * inv121 - my2;
            float vxy = Sxy[j] * inv121 - mxy;
            float num = (2.0f * mxy + C1_SSIM) * (2.0f * vxy + C2_SSIM);
            float den = (mx2 + my2 + C1_SSIM) * (vx + vy + C2_SSIM);
            loss += __fdividef(num, den);
        }

        apply(sub, -1.0f);                      // V covers rows [ro-4, ro+5]
        curA = nxtA;
    }

    // wave-level reduction, one atomic per wave
#pragma unroll
    for (int off = 32; off > 0; off >>= 1)
        loss += __shfl_down(loss, off, 64);
    if (tx == 0) atomicAdd(acc, loss);

    // last block finalizes (completion counter; atomics are device-scope)
    __syncthreads();                 // all 4 waves' atomicAdds issued
    if (threadIdx.x == 0) {
        __threadfence();
        unsigned int old = atomicAdd(cnt, 1u);
        if (old == NBLOCKS - 1) {
            float total = atomicAdd(acc, 0.0f);   // atomic read, fully ordered
            out[0] = 1.0f - total * (1.0f / ((float)N_IMG * IMG_H * IMG_W));
        }
    }
}

extern "C" void kernel_launch(void* const* d_in, const int* in_sizes, int n_in,
                              void* d_out, int out_size, void* d_ws, size_t ws_size,
                              hipStream_t stream) {
    const float* x = (const float*)d_in[0];
    const float* y = (const float*)d_in[1];
    // d_in[2] is the uniform 11x11/121 kernel; its value is compile-time known.
    float*        acc = (float*)d_ws;
    unsigned int* cnt = (unsigned int*)d_ws + 1;

    hipMemsetAsync(d_ws, 0, 8, stream);   // zero acc + counter
    ssim_fused<<<NBLOCKS, 256, 0, stream>>>(x, y, acc, cnt, (float*)d_out);
}

// Round 5
// 191.357 us; speedup vs baseline: 1.2780x; 1.2780x over previous
//
#include <hip/hip_runtime.h>

// SSIM loss, fused single-pass separable box filter — shuffle halo, no atomics.
// R5: R2's known-good body; reduction rewritten to contention-free stores.
// Theory: R1-R4 all pinned at ~140us with every pipe idle because the 4096
// same-address atomicAdds (+1024 counter atomics) serialize at ~30ns each at
// the coherence point, and waves can't retire until their atomic drains.
// Now: wave shfl-reduce -> LDS -> ONE plain store per block -> tiny reduce
// kernel over 1024 partials.
//
// Grid: 1024 blocks = 64 images x 16 row-bands. Block = 256 threads = 4
// independent waves. Each wave owns SH=8 output rows x 512 cols; each lane
// owns 8 contiguous columns. Vertical 11-row window: per-lane register
// running sums (slide add/sub; sub-row re-read is cache-resident).
// Horizontal 11-col window: 5-float halo per side via __shfl.

#define IMG_H 512
#define IMG_W 512
#define N_IMG 64
#define RAD   5
#define SH    8
#define NBAND 16
#define NBLOCKS (N_IMG * NBAND)

#define C1_SSIM 1.0e-4f
#define C2_SSIM 9.0e-4f

__global__ __launch_bounds__(256) void ssim_fused(const float* __restrict__ x,
                                                  const float* __restrict__ y,
                                                  float* __restrict__ part)
{
    const int tx  = threadIdx.x & 63;
    const int ts  = threadIdx.x >> 6;
    const int img = blockIdx.x >> 4;          // / NBAND
    const int bnd = blockIdx.x & (NBAND - 1);
    const int r0  = bnd * (4 * SH) + ts * SH;
    const int c0  = tx * 8;

    const float* __restrict__ xb = x + (size_t)img * (IMG_H * IMG_W) + c0;
    const float* __restrict__ yb = y + (size_t)img * (IMG_H * IMG_W) + c0;

    float Vx[8], Vy[8], Vxx[8], Vyy[8], Vxy[8];
#pragma unroll
    for (int j = 0; j < 8; ++j) { Vx[j] = 0.f; Vy[j] = 0.f; Vxx[j] = 0.f; Vyy[j] = 0.f; Vxy[j] = 0.f; }

    // add or subtract one input row into the running vertical sums
    auto accum = [&](int ri, bool add) {
        const float4* xr = (const float4*)(xb + (size_t)ri * IMG_W);
        const float4* yr = (const float4*)(yb + (size_t)ri * IMG_W);
        float4 x0 = xr[0], x1 = xr[1];
        float4 y0 = yr[0], y1 = yr[1];
        float xs[8] = {x0.x, x0.y, x0.z, x0.w, x1.x, x1.y, x1.z, x1.w};
        float ys[8] = {y0.x, y0.y, y0.z, y0.w, y1.x, y1.y, y1.z, y1.w};
        if (add) {
#pragma unroll
            for (int j = 0; j < 8; ++j) {
                Vx[j]  += xs[j];
                Vy[j]  += ys[j];
                Vxx[j] = fmaf(xs[j], xs[j], Vxx[j]);
                Vyy[j] = fmaf(ys[j], ys[j], Vyy[j]);
                Vxy[j] = fmaf(xs[j], ys[j], Vxy[j]);
            }
        } else {
#pragma unroll
            for (int j = 0; j < 8; ++j) {
                Vx[j]  -= xs[j];
                Vy[j]  -= ys[j];
                Vxx[j] = fmaf(-xs[j], xs[j], Vxx[j]);
                Vyy[j] = fmaf(-ys[j], ys[j], Vyy[j]);
                Vxy[j] = fmaf(-xs[j], ys[j], Vxy[j]);
            }
        }
    };

    // 11-tap sliding horizontal sums; halo via lane+-1 shuffles
    auto hsum = [&](const float (&V)[8], float (&S)[8]) {
        float w[18];
#pragma unroll
        for (int k = 0; k < 5; ++k) {
            float l = __shfl_up(V[3 + k], 1, 64);
            w[k] = (tx == 0) ? 0.f : l;
        }
#pragma unroll
        for (int j = 0; j < 8; ++j) w[5 + j] = V[j];
#pragma unroll
        for (int k = 0; k < 5; ++k) {
            float r = __shfl_down(V[k], 1, 64);
            w[13 + k] = (tx == 63) ? 0.f : r;
        }
        float s = 0.f;
#pragma unroll
        for (int t = 0; t < 11; ++t) s += w[t];
        S[0] = s;
#pragma unroll
        for (int j = 1; j < 8; ++j) { s += w[j + 10] - w[j - 1]; S[j] = s; }
    };

    // warm-up: rows [r0-5, r0+4] (invariant: V holds rows ro-5..ro+4 at loop head)
    for (int ri = r0 - RAD; ri < r0 + RAD; ++ri)
        if (ri >= 0 && ri < IMG_H) accum(ri, true);

    const float inv121 = 1.0f / 121.0f;
    float loss = 0.0f;

    for (int ro = r0; ro < r0 + SH; ++ro) {
        int ra = ro + RAD;
        if (ra < IMG_H) accum(ra, true);

        float Sx[8], Sy[8], Sxx[8], Syy[8], Sxy[8];
        hsum(Vx,  Sx);
        hsum(Vy,  Sy);
        hsum(Vxx, Sxx);
        hsum(Vyy, Syy);
        hsum(Vxy, Sxy);

#pragma unroll
        for (int j = 0; j < 8; ++j) {
            float mx  = Sx[j] * inv121;
            float my  = Sy[j] * inv121;
            float mx2 = mx * mx;
            float my2 = my * my;
            float mxy = mx * my;
            float vx  = Sxx[j] * inv121 - mx2;
            float vy  = Syy[j] * inv121 - my2;
            float vxy = Sxy[j] * inv121 - mxy;
            float num = (2.0f * mxy + C1_SSIM) * (2.0f * vxy + C2_SSIM);
            float den = (mx2 + my2 + C1_SSIM) * (vx + vy + C2_SSIM);
            loss += __fdividef(num, den);
        }

        int rs = ro - RAD;
        if (rs >= 0) accum(rs, false);
    }

    // reduction: wave shfl-reduce -> LDS -> one plain store per block.
    // No atomics: 1024 distinct addresses, nothing serializes.
#pragma unroll
    for (int off = 32; off > 0; off >>= 1)
        loss += __shfl_down(loss, off, 64);

    __shared__ float pr[4];
    if (tx == 0) pr[ts] = loss;
    __syncthreads();
    if (threadIdx.x == 0)
        part[blockIdx.x] = (pr[0] + pr[1]) + (pr[2] + pr[3]);
}

// single-block finisher: reduce 1024 partials (4 KB) and write the loss
__global__ __launch_bounds__(256) void ssim_reduce(const float* __restrict__ part,
                                                   float* __restrict__ out)
{
    const int t  = threadIdx.x;
    const int tx = t & 63;
    float s = part[t] + part[t + 256] + part[t + 512] + part[t + 768];
#pragma unroll
    for (int off = 32; off > 0; off >>= 1)
        s += __shfl_down(s, off, 64);
    __shared__ float ws[4];
    if (tx == 0) ws[t >> 6] = s;
    __syncthreads();
    if (t == 0) {
        float total = (ws[0] + ws[1]) + (ws[2] + ws[3]);
        out[0] = 1.0f - total * (1.0f / ((float)N_IMG * IMG_H * IMG_W));
    }
}

extern "C" void kernel_launch(void* const* d_in, const int* in_sizes, int n_in,
                              void* d_out, int out_size, void* d_ws, size_t ws_size,
                              hipStream_t stream) {
    const float* x = (const float*)d_in[0];
    const float* y = (const float*)d_in[1];
    // d_in[2] is the uniform 11x11/121 kernel; its value is compile-time known.
    float* part = (float*)d_ws;           // 1024 floats, all written each call

    ssim_fused<<<NBLOCKS, 256, 0, stream>>>(x, y, part);
    ssim_reduce<<<1, 256, 0, stream>>>(part, (float*)d_out);
}